// Round 4
// baseline (395.186 us; speedup 1.0000x reference)
//
#include <hip/hip_runtime.h>
#include <cstdint>

#define SEQ    8192
#define DIN    1024
#define DOUT   128
#define NSPLIT 8
#define KVTILE 64
#define SM_SCALE 0.08838834764831845f   // 1/sqrt(128)
#define LOG2E    1.4426950408889634f
#define RESCALE_THR 8.0f

typedef unsigned short u16;
typedef __bf16 bf16x8 __attribute__((ext_vector_type(8)));
typedef float  f32x4  __attribute__((ext_vector_type(4)));
typedef unsigned short u16x8 __attribute__((ext_vector_type(8)));
typedef unsigned short u16x4 __attribute__((ext_vector_type(4)));

// f32 -> bf16 via native cast (compiler emits v_cvt_pk_bf16_f32, RNE)
__device__ __forceinline__ u16 bfc(float f) {
  return __builtin_bit_cast(u16, (__bf16)f);
}
__device__ __forceinline__ float bf2f(u16 u) {
  union { uint32_t u; float f; } c; c.u = ((uint32_t)u) << 16; return c.f;
}

__device__ __forceinline__ bf16x8 ldsu8(const u16* base, int byteoff) {
  return __builtin_bit_cast(bf16x8,
    *reinterpret_cast<const u16x8*>(reinterpret_cast<const char*>(base) + byteoff));
}
__device__ __forceinline__ bf16x8 glbu8(const u16* p) {
  return __builtin_bit_cast(bf16x8, *reinterpret_cast<const u16x8*>(p));
}

// ---------------------------------------------------------------- kernel 0
// W [1024][128] fp32  ->  Wt [3][128][1024] bf16 (transposed)
__global__ __launch_bounds__(256) void k_wtrans(const float* __restrict__ wq,
                                                const float* __restrict__ wk,
                                                const float* __restrict__ wv,
                                                u16* __restrict__ Wt) {
  const float* w = (blockIdx.y == 0) ? wq : (blockIdx.y == 1) ? wk : wv;
  int idx = blockIdx.x * 256 + threadIdx.x;      // over DIN*DOUT
  int k = idx >> 7, n = idx & 127;
  Wt[(size_t)blockIdx.y * (DOUT * DIN) + (size_t)n * DIN + k] = bfc(w[idx]);
}

// ---------------------------------------------------------------- kernel 1
// Fused GEMM C[8192][384] = X[8192][1024] * [Wq|Wk|Wv].
// No LDS, no barriers. Block 512 thr (8 waves); M-tile 16; each wave owns
// 16 rows x 48 cols (acc = 3 x f32x4 = 12 VGPR). Grid 512 -> 2 blocks/CU
// = 16 waves/CU (50% occupancy; was 25%).
__global__ __launch_bounds__(512) void k_qkv(const float* __restrict__ x,
                                             const u16* __restrict__ Wt,
                                             u16* __restrict__ Q,
                                             u16* __restrict__ K,
                                             u16* __restrict__ Vt) {
  const int tid  = threadIdx.x;
  const int lane = tid & 63, wave = tid >> 6;
  const int lm   = lane & 15, g = lane >> 4;
  const int nr   = wave * 48;          // n-range base (48 cols per wave)
  const int m0   = blockIdx.x * 16;
  const int mrow = m0 + lm;
  const float* xp = x + (size_t)mrow * DIN + 8 * g;

  f32x4 acc[3];
#pragma unroll
  for (int nb = 0; nb < 3; ++nb) acc[nb] = (f32x4){0.f, 0.f, 0.f, 0.f};

  for (int kc = 0; kc < DIN / 64; ++kc) {
    bf16x8 a[2];
#pragma unroll
    for (int t = 0; t < 2; ++t) {
      const float* p = xp + kc * 64 + t * 32;
      float4 lo = *reinterpret_cast<const float4*>(p);
      float4 hi = *reinterpret_cast<const float4*>(p + 4);
      u16x8 v = { bfc(lo.x), bfc(lo.y), bfc(lo.z), bfc(lo.w),
                  bfc(hi.x), bfc(hi.y), bfc(hi.z), bfc(hi.w) };
      a[t] = __builtin_bit_cast(bf16x8, v);
    }
#pragma unroll
    for (int nb = 0; nb < 3; ++nb) {
      const u16* wp = Wt + (size_t)(nr + nb * 16 + lm) * DIN + kc * 64 + 8 * g;
#pragma unroll
      for (int t = 0; t < 2; ++t) {
        bf16x8 b = glbu8(wp + t * 32);
        acc[nb] = __builtin_amdgcn_mfma_f32_16x16x32_bf16(a[t], b, acc[nb], 0, 0, 0);
      }
    }
  }

  // epilogue: C/D layout col=lane&15, row=(lane>>4)*4+reg  [HW-verified]
  // n-blocks are 16-aligned -> never straddle a 128 boundary -> uniform branch.
#pragma unroll
  for (int nb = 0; nb < 3; ++nb) {
    int n = nr + nb * 16 + lm;
    int which = n >> 7, col = n & 127;
#pragma unroll
    for (int r = 0; r < 4; ++r) {
      int m = m0 + g * 4 + r;
      u16 val = bfc(acc[nb][r]);
      if (which == 0)       Q[(size_t)m * DOUT + col] = val;
      else if (which == 1)  K[(size_t)m * DOUT + col] = val;
      else                  Vt[(size_t)col * SEQ + m] = val;
    }
  }
}

// ---------------------------------------------------------------- kernel 2
// Flash attention partials — BARRIER-FREE main loop.
// K/V fragments read MFMA-direct from global (L2-resident: 512 KB/split,
// shared across blocks on an XCD; m169 lesson — don't stage what caches).
// Only LDS use: per-wave P buffer (8 KB/block), ordered by lgkmcnt(0).
// Block 256 (4 waves), Q-tile 64; grid (SEQ/64, NSPLIT=8) = 1024 blocks
// = 4 blocks/CU = 16 waves/CU, all independent.
__global__ __launch_bounds__(256) void k_attn(const u16* __restrict__ Q,
                                              const u16* __restrict__ K,
                                              const u16* __restrict__ Vt,
                                              u16* __restrict__ Op,
                                              float* __restrict__ Mb,
                                              float* __restrict__ Lb) {
  __shared__ __attribute__((aligned(16))) u16 Ps[4][16 * 64];  // 8 KB
  const int tid  = threadIdx.x;
  const int lane = tid & 63, wave = tid >> 6;
  const int lm   = lane & 15, g = lane >> 4;
  const int m0   = blockIdx.x * 64;
  const int split = blockIdx.y;
  const int kvbase = split * (SEQ / NSPLIT);

  // Q fragments, resident in registers for the whole kernel
  bf16x8 qf[4];
  {
    const u16* qp = Q + (size_t)(m0 + wave * 16 + lm) * DOUT + 8 * g;
#pragma unroll
    for (int t = 0; t < 4; ++t) qf[t] = glbu8(qp + t * 32);
  }

  f32x4 o[8];
#pragma unroll
  for (int nb = 0; nb < 8; ++nb) o[nb] = (f32x4){0.f, 0.f, 0.f, 0.f};
  float mr[4] = {-1e30f, -1e30f, -1e30f, -1e30f};
  float lr[4] = {0.f, 0.f, 0.f, 0.f};

  u16* pw = Ps[wave];

  for (int it = 0; it < (SEQ / NSPLIT) / KVTILE; ++it) {
    const int kv0 = kvbase + it * KVTILE;

    // ---- S = Q K^T * scale  (4 col-blocks x K=128); K direct from global
    f32x4 s[4];
#pragma unroll
    for (int cb = 0; cb < 4; ++cb) {
      f32x4 a = (f32x4){0.f, 0.f, 0.f, 0.f};
      const u16* kp = K + (size_t)(kv0 + cb * 16 + lm) * DOUT + 8 * g;
#pragma unroll
      for (int t = 0; t < 4; ++t) {
        bf16x8 b = glbu8(kp + t * 32);
        a = __builtin_amdgcn_mfma_f32_16x16x32_bf16(qf[t], b, a, 0, 0, 0);
      }
      s[cb] = a * SM_SCALE;
    }

    // ---- online softmax, defer-max (T13). Row owned by lane: q = g*4+r.
    float rmax[4];
#pragma unroll
    for (int r = 0; r < 4; ++r) {
      float rm = fmaxf(fmaxf(s[0][r], s[1][r]), fmaxf(s[2][r], s[3][r]));
#pragma unroll
      for (int off = 1; off < 16; off <<= 1) rm = fmaxf(rm, __shfl_xor(rm, off));
      rmax[r] = rm;
    }
    float exc = fmaxf(fmaxf(rmax[0] - mr[0], rmax[1] - mr[1]),
                      fmaxf(rmax[2] - mr[2], rmax[3] - mr[3]));
    if (__any(exc > RESCALE_THR)) {     // first tile + rare growth
#pragma unroll
      for (int r = 0; r < 4; ++r) {
        float mn = fmaxf(mr[r], rmax[r]);
        float alpha = exp2f((mr[r] - mn) * LOG2E);
        mr[r] = mn;
        lr[r] *= alpha;
#pragma unroll
        for (int nb = 0; nb < 8; ++nb) o[nb][r] *= alpha;
      }
    }
    float pv[4][4];
#pragma unroll
    for (int r = 0; r < 4; ++r) {
      float rs = 0.f;
#pragma unroll
      for (int cb = 0; cb < 4; ++cb) {
        float p = exp2f((s[cb][r] - mr[r]) * LOG2E);   // bounded by e^THR
        pv[cb][r] = p;
        rs += p;
      }
#pragma unroll
      for (int off = 1; off < 16; off <<= 1) rs += __shfl_xor(rs, off);
      lr[r] += rs;
    }

    // ---- P -> per-wave LDS (bf16, swizzled); wave-private, no barrier
#pragma unroll
    for (int cb = 0; cb < 4; ++cb)
#pragma unroll
      for (int r = 0; r < 4; ++r) {
        int row = g * 4 + r, col = cb * 16 + lm;
        *reinterpret_cast<u16*>(reinterpret_cast<char*>(pw) + row * 128 +
                                ((col * 2) ^ ((row & 7) << 4))) = bfc(pv[cb][r]);
      }
    // order P writes before P reads (per-wave DS is in-order; drain then read)
    asm volatile("s_waitcnt lgkmcnt(0)" ::: "memory");
    __builtin_amdgcn_sched_barrier(0);

    // ---- O += P V   (A = P rows from LDS, B = V^T rows direct from global)
#pragma unroll
    for (int t = 0; t < 2; ++t) {
      bf16x8 pa = ldsu8(pw, lm * 128 +
                            (((t * 32 + 8 * g) * 2) ^ ((lm & 7) << 4)));
#pragma unroll
      for (int nb = 0; nb < 8; ++nb) {
        bf16x8 vb = glbu8(Vt + (size_t)(nb * 16 + lm) * SEQ + kv0 + t * 32 + 8 * g);
        o[nb] = __builtin_amdgcn_mfma_f32_16x16x32_bf16(pa, vb, o[nb], 0, 0, 0);
      }
    }
  }

  // ---- store partials (bf16)
  const size_t ob = (size_t)split * SEQ * DOUT;
#pragma unroll
  for (int nb = 0; nb < 8; ++nb)
#pragma unroll
    for (int r = 0; r < 4; ++r) {
      int m = m0 + wave * 16 + g * 4 + r;
      Op[ob + (size_t)m * DOUT + nb * 16 + lm] = bfc(o[nb][r]);
    }
  if (lm == 0) {
#pragma unroll
    for (int r = 0; r < 4; ++r) {
      int m = m0 + wave * 16 + g * 4 + r;
      Mb[split * SEQ + m] = mr[r];
      Lb[split * SEQ + m] = lr[r];
    }
  }
}

// ---------------------------------------------------------------- kernel 3
__global__ __launch_bounds__(256) void k_combine(const u16* __restrict__ Op,
                                                 const float* __restrict__ Mb,
                                                 const float* __restrict__ Lb,
                                                 float* __restrict__ out) {
  int idx = blockIdx.x * 256 + threadIdx.x;   // over SEQ*DOUT
  int srow = idx >> 7;
  float M = -1e30f;
#pragma unroll
  for (int s = 0; s < NSPLIT; ++s) M = fmaxf(M, Mb[s * SEQ + srow]);
  float num = 0.f, den = 0.f;
  const size_t st = (size_t)SEQ * DOUT;
#pragma unroll
  for (int s = 0; s < NSPLIT; ++s) {
    float e = exp2f((Mb[s * SEQ + srow] - M) * LOG2E);
    den += Lb[s * SEQ + srow] * e;
    num += bf2f(Op[s * st + idx]) * e;
  }
  out[idx] = num / den;
}

// ---------------------------------------------------------------- launch
extern "C" void kernel_launch(void* const* d_in, const int* in_sizes, int n_in,
                              void* d_out, int out_size, void* d_ws, size_t ws_size,
                              hipStream_t stream) {
  const float* x  = (const float*)d_in[0];
  const float* wq = (const float*)d_in[1];
  const float* wk = (const float*)d_in[2];
  const float* wv = (const float*)d_in[3];
  char* ws = (char*)d_ws;

  // workspace layout (bytes), total 23.25 MiB (unchanged from passing rounds):
  //  [0,    768K)          Wt bf16 [3][128][1024]
  //  [768K, +2M)           Q  bf16 [8192][128]
  //  [768K+2M,  +2M)       K  bf16 [8192][128]
  //  [768K+4M,  +2M)       Vt bf16 [128][8192]
  //  [768K+6M,  +16M)      Op bf16 [8][8192][128]
  //  [768K+22M, +256K)     Mb f32 [8][8192]
  //  [768K+22M+256K,+256K) Lb f32 [8][8192]
  const size_t MB = (size_t)1 << 20;
  u16*   Wt = (u16*)(ws);
  u16*   Q  = (u16*)(ws + 768 * 1024);
  u16*   K  = (u16*)(ws + 768 * 1024 + 2 * MB);
  u16*   Vt = (u16*)(ws + 768 * 1024 + 4 * MB);
  u16*   Op = (u16*)(ws + 768 * 1024 + 6 * MB);
  float* Mb = (float*)(ws + 768 * 1024 + 22 * MB);
  float* Lb = (float*)(ws + 768 * 1024 + 22 * MB + 256 * 1024);
  float* out = (float*)d_out;

  k_wtrans<<<dim3((DIN * DOUT) / 256, 3), 256, 0, stream>>>(wq, wk, wv, Wt);
  k_qkv<<<dim3(SEQ / 16), 512, 0, stream>>>(x, Wt, Q, K, Vt);
  k_attn<<<dim3(SEQ / 64, NSPLIT), 256, 0, stream>>>(Q, K, Vt, Op, Mb, Lb);
  k_combine<<<dim3((SEQ * DOUT) / 256), 256, 0, stream>>>(Op, Mb, Lb, out);
}

// Round 5
// 180.146 us; speedup vs baseline: 2.1937x; 2.1937x over previous
//
#include <hip/hip_runtime.h>
#include <cstdint>

#define SEQ    8192
#define DIN    1024
#define DOUT   128
#define NSPLIT 4
#define KVTILE 64
#define SM_SCALE 0.08838834764831845f   // 1/sqrt(128)
#define LOG2E    1.4426950408889634f
#define RESCALE_THR 8.0f

typedef unsigned short u16;
typedef __bf16 bf16x8 __attribute__((ext_vector_type(8)));
typedef float  f32x4  __attribute__((ext_vector_type(4)));
typedef unsigned short u16x8 __attribute__((ext_vector_type(8)));
typedef unsigned short u16x4 __attribute__((ext_vector_type(4)));

// f32 -> bf16 via native cast (compiler emits v_cvt_pk_bf16_f32, RNE)
__device__ __forceinline__ u16 bfc(float f) {
  return __builtin_bit_cast(u16, (__bf16)f);
}
__device__ __forceinline__ float bf2f(u16 u) {
  union { uint32_t u; float f; } c; c.u = ((uint32_t)u) << 16; return c.f;
}

__device__ __forceinline__ bf16x8 ldsu8(const u16* base, int byteoff) {
  return __builtin_bit_cast(bf16x8,
    *reinterpret_cast<const u16x8*>(reinterpret_cast<const char*>(base) + byteoff));
}
__device__ __forceinline__ bf16x8 glbu8(const u16* p) {
  return __builtin_bit_cast(bf16x8, *reinterpret_cast<const u16x8*>(p));
}

// async global->LDS DMA, 16B per lane; LDS dest = base + lane*16 (linear).
__device__ __forceinline__ void gload_lds16(const void* g, void* l) {
  __builtin_amdgcn_global_load_lds(
      (const __attribute__((address_space(1))) void*)g,
      (__attribute__((address_space(3))) void*)l, 16, 0, 0);
}

// ---------------------------------------------------------------- kernel 0
// W [1024][128] fp32  ->  Wt [3][128][1024] bf16 (transposed)
__global__ __launch_bounds__(256) void k_wtrans(const float* __restrict__ wq,
                                                const float* __restrict__ wk,
                                                const float* __restrict__ wv,
                                                u16* __restrict__ Wt) {
  const float* w = (blockIdx.y == 0) ? wq : (blockIdx.y == 1) ? wk : wv;
  int idx = blockIdx.x * 256 + threadIdx.x;      // over DIN*DOUT
  int k = idx >> 7, n = idx & 127;
  Wt[(size_t)blockIdx.y * (DOUT * DIN) + (size_t)n * DIN + k] = bfc(w[idx]);
}

// ---------------------------------------------------------------- kernel 1
// Fused GEMM C[8192][384] = X[8192][1024] * [Wq|Wk|Wv].  (round-4 version,
// measured ~40us) No LDS/barriers; 512 thr (8 waves); M-tile 16; wave owns
// 16 rows x 48 cols; grid 512 -> 16 waves/CU.
__global__ __launch_bounds__(512) void k_qkv(const float* __restrict__ x,
                                             const u16* __restrict__ Wt,
                                             u16* __restrict__ Q,
                                             u16* __restrict__ K,
                                             u16* __restrict__ Vt) {
  const int tid  = threadIdx.x;
  const int lane = tid & 63, wave = tid >> 6;
  const int lm   = lane & 15, g = lane >> 4;
  const int nr   = wave * 48;          // n-range base (48 cols per wave)
  const int m0   = blockIdx.x * 16;
  const int mrow = m0 + lm;
  const float* xp = x + (size_t)mrow * DIN + 8 * g;

  f32x4 acc[3];
#pragma unroll
  for (int nb = 0; nb < 3; ++nb) acc[nb] = (f32x4){0.f, 0.f, 0.f, 0.f};

  for (int kc = 0; kc < DIN / 64; ++kc) {
    bf16x8 a[2];
#pragma unroll
    for (int t = 0; t < 2; ++t) {
      const float* p = xp + kc * 64 + t * 32;
      float4 lo = *reinterpret_cast<const float4*>(p);
      float4 hi = *reinterpret_cast<const float4*>(p + 4);
      u16x8 v = { bfc(lo.x), bfc(lo.y), bfc(lo.z), bfc(lo.w),
                  bfc(hi.x), bfc(hi.y), bfc(hi.z), bfc(hi.w) };
      a[t] = __builtin_bit_cast(bf16x8, v);
    }
#pragma unroll
    for (int nb = 0; nb < 3; ++nb) {
      const u16* wp = Wt + (size_t)(nr + nb * 16 + lm) * DIN + kc * 64 + 8 * g;
#pragma unroll
      for (int t = 0; t < 2; ++t) {
        bf16x8 b = glbu8(wp + t * 32);
        acc[nb] = __builtin_amdgcn_mfma_f32_16x16x32_bf16(a[t], b, acc[nb], 0, 0, 0);
      }
    }
  }

  // epilogue: C/D layout col=lane&15, row=(lane>>4)*4+reg  [HW-verified]
#pragma unroll
  for (int nb = 0; nb < 3; ++nb) {
    int n = nr + nb * 16 + lm;
    int which = n >> 7, col = n & 127;   // uniform per n-block
#pragma unroll
    for (int r = 0; r < 4; ++r) {
      int m = m0 + g * 4 + r;
      u16 val = bfc(acc[nb][r]);
      if (which == 0)       Q[(size_t)m * DOUT + col] = val;
      else if (which == 1)  K[(size_t)m * DOUT + col] = val;
      else                  Vt[(size_t)col * SEQ + m] = val;
    }
  }
}

// ---------------------------------------------------------------- kernel 2
// Flash attention partials. Round-2 proven structure (LDS-staged K/V) +
// (a) global_load_lds width-16 staging, swizzle on the GLOBAL source
//     (linear LDS dest; XOR involution => read code unchanged),
// (b) 2-phase double-buffer: STAGE(next) issued before compute, ONE
//     vmcnt(0)+barrier per iter,
// (c) wave-private P buffer ordered by lgkmcnt(0) (no block barrier).
// Block 256 (4 waves), Q-tile 64, KV-tile 64, grid (SEQ/64, NSPLIT=4).
// LDS 72 KB -> 2 blocks/CU (matches measured residency of the 40KB version).
__global__ __launch_bounds__(256) void k_attn(const u16* __restrict__ Q,
                                              const u16* __restrict__ K,
                                              const u16* __restrict__ Vt,
                                              u16* __restrict__ Op,
                                              float* __restrict__ Mb,
                                              float* __restrict__ Lb) {
  __shared__ __attribute__((aligned(16))) u16 Ks[2][64 * 128];    // 2x16 KB
  __shared__ __attribute__((aligned(16))) u16 Vts[2][128 * 64];   // 2x16 KB
  __shared__ __attribute__((aligned(16))) u16 Ps[4][16 * 64];     //   8 KB
  const int tid  = threadIdx.x;
  const int lane = tid & 63, wave = tid >> 6;
  const int lm   = lane & 15, g = lane >> 4;
  const int m0   = blockIdx.x * 64;
  const int split = blockIdx.y;
  const int kvbase = split * (SEQ / NSPLIT);
  const int NIT = (SEQ / NSPLIT) / KVTILE;

  // ---- STAGE: wave w stages K rows [w*16,w*16+16) and Vt rows [w*32,w*32+32)
  // via 4+4 global_load_lds (each = 64 lanes x 16B = 1KB = 4 K-rows / 8 V-rows).
  // LDS linear; global source pre-swizzled by ((row&7)<<4).
  auto stage = [&](int buf, int kv0) {
#pragma unroll
    for (int i = 0; i < 4; ++i) {
      int krow = wave * 16 + i * 4 + (lane >> 4);           // lane>>4 in 0..3
      const char* gk = (const char*)K + ((size_t)(kv0 + krow) << 8) +
                       ((((lane & 15) << 4)) ^ ((krow & 7) << 4));
      gload_lds16(gk, &Ks[buf][wave * 2048 + i * 512]);
      int vrow = wave * 32 + i * 8 + (lane >> 3);           // lane>>3 in 0..7
      const char* gv = (const char*)Vt + (size_t)vrow * (SEQ * 2) +
                       (size_t)kv0 * 2 +
                       ((((lane & 7) << 4)) ^ ((vrow & 7) << 4));
      gload_lds16(gv, &Vts[buf][wave * 2048 + i * 512]);
    }
  };

  // Q fragments, resident in registers for the whole kernel
  bf16x8 qf[4];

  // prologue: stage tile 0, load Q, drain, barrier
  stage(0, kvbase);
  {
    const u16* qp = Q + (size_t)(m0 + wave * 16 + lm) * DOUT + 8 * g;
#pragma unroll
    for (int t = 0; t < 4; ++t) qf[t] = glbu8(qp + t * 32);
  }
  asm volatile("s_waitcnt vmcnt(0)" ::: "memory");
  __syncthreads();

  f32x4 o[8];
#pragma unroll
  for (int nb = 0; nb < 8; ++nb) o[nb] = (f32x4){0.f, 0.f, 0.f, 0.f};
  float mr[4] = {-1e30f, -1e30f, -1e30f, -1e30f};
  float lr[4] = {0.f, 0.f, 0.f, 0.f};

  u16* pw = Ps[wave];
  int cur = 0;

  for (int it = 0; it < NIT; ++it) {
    // issue next-tile staging; loads fly under this iter's compute
    if (it + 1 < NIT) stage(cur ^ 1, kvbase + (it + 1) * KVTILE);

    const u16* ks = Ks[cur];
    const u16* vs = Vts[cur];

    // ---- S = Q K^T * scale  (4 col-blocks x K=128)
    f32x4 s[4];
#pragma unroll
    for (int cb = 0; cb < 4; ++cb) {
      f32x4 a = (f32x4){0.f, 0.f, 0.f, 0.f};
      int krow = cb * 16 + lm;
#pragma unroll
      for (int t = 0; t < 4; ++t) {
        bf16x8 b = ldsu8(ks, krow * 256 +
                             (((t * 32 + 8 * g) * 2) ^ ((krow & 7) << 4)));
        a = __builtin_amdgcn_mfma_f32_16x16x32_bf16(qf[t], b, a, 0, 0, 0);
      }
      s[cb] = a * SM_SCALE;
    }

    // ---- online softmax, defer-max (T13). Row owned by lane: q = g*4+r.
    float rmax[4];
#pragma unroll
    for (int r = 0; r < 4; ++r) {
      float rm = fmaxf(fmaxf(s[0][r], s[1][r]), fmaxf(s[2][r], s[3][r]));
#pragma unroll
      for (int off = 1; off < 16; off <<= 1) rm = fmaxf(rm, __shfl_xor(rm, off));
      rmax[r] = rm;
    }
    float exc = fmaxf(fmaxf(rmax[0] - mr[0], rmax[1] - mr[1]),
                      fmaxf(rmax[2] - mr[2], rmax[3] - mr[3]));
    if (__any(exc > RESCALE_THR)) {     // first tile + rare growth
#pragma unroll
      for (int r = 0; r < 4; ++r) {
        float mn = fmaxf(mr[r], rmax[r]);
        float alpha = exp2f((mr[r] - mn) * LOG2E);
        mr[r] = mn;
        lr[r] *= alpha;
#pragma unroll
        for (int nb = 0; nb < 8; ++nb) o[nb][r] *= alpha;
      }
    }
    float pv[4][4];
#pragma unroll
    for (int r = 0; r < 4; ++r) {
      float rs = 0.f;
#pragma unroll
      for (int cb = 0; cb < 4; ++cb) {
        float p = exp2f((s[cb][r] - mr[r]) * LOG2E);   // bounded by e^THR
        pv[cb][r] = p;
        rs += p;
      }
#pragma unroll
      for (int off = 1; off < 16; off <<= 1) rs += __shfl_xor(rs, off);
      lr[r] += rs;
    }

    // ---- P -> per-wave LDS (bf16, swizzled); wave-private, no barrier
#pragma unroll
    for (int cb = 0; cb < 4; ++cb)
#pragma unroll
      for (int r = 0; r < 4; ++r) {
        int row = g * 4 + r, col = cb * 16 + lm;
        *reinterpret_cast<u16*>(reinterpret_cast<char*>(pw) + row * 128 +
                                ((col * 2) ^ ((row & 7) << 4))) = bfc(pv[cb][r]);
      }
    // order P writes before P reads (per-wave DS in-order; rule-18 fence)
    asm volatile("s_waitcnt lgkmcnt(0)" ::: "memory");
    __builtin_amdgcn_sched_barrier(0);

    // ---- O += P V   (A = P rows, B = V^T rows = d-columns)
#pragma unroll
    for (int t = 0; t < 2; ++t) {
      bf16x8 pa = ldsu8(pw, lm * 128 +
                            (((t * 32 + 8 * g) * 2) ^ ((lm & 7) << 4)));
#pragma unroll
      for (int nb = 0; nb < 8; ++nb) {
        int vrow = nb * 16 + lm;
        bf16x8 vb = ldsu8(vs, vrow * 128 +
                              (((t * 32 + 8 * g) * 2) ^ ((vrow & 7) << 4)));
        o[nb] = __builtin_amdgcn_mfma_f32_16x16x32_bf16(pa, vb, o[nb], 0, 0, 0);
      }
    }

    // next tile landed; everyone done reading cur
    asm volatile("s_waitcnt vmcnt(0)" ::: "memory");
    __syncthreads();
    cur ^= 1;
  }

  // ---- store partials (bf16)
  const size_t ob = (size_t)split * SEQ * DOUT;
#pragma unroll
  for (int nb = 0; nb < 8; ++nb)
#pragma unroll
    for (int r = 0; r < 4; ++r) {
      int m = m0 + wave * 16 + g * 4 + r;
      Op[ob + (size_t)m * DOUT + nb * 16 + lm] = bfc(o[nb][r]);
    }
  if (lm == 0) {
#pragma unroll
    for (int r = 0; r < 4; ++r) {
      int m = m0 + wave * 16 + g * 4 + r;
      Mb[split * SEQ + m] = mr[r];
      Lb[split * SEQ + m] = lr[r];
    }
  }
}

// ---------------------------------------------------------------- kernel 3
__global__ __launch_bounds__(256) void k_combine(const u16* __restrict__ Op,
                                                 const float* __restrict__ Mb,
                                                 const float* __restrict__ Lb,
                                                 float* __restrict__ out) {
  int idx = blockIdx.x * 256 + threadIdx.x;   // over SEQ*DOUT
  int srow = idx >> 7;
  float M = -1e30f;
#pragma unroll
  for (int s = 0; s < NSPLIT; ++s) M = fmaxf(M, Mb[s * SEQ + srow]);
  float num = 0.f, den = 0.f;
  const size_t st = (size_t)SEQ * DOUT;
#pragma unroll
  for (int s = 0; s < NSPLIT; ++s) {
    float e = exp2f((Mb[s * SEQ + srow] - M) * LOG2E);
    den += Lb[s * SEQ + srow] * e;
    num += bf2f(Op[s * st + idx]) * e;
  }
  out[idx] = num / den;
}

// ---------------------------------------------------------------- launch
extern "C" void kernel_launch(void* const* d_in, const int* in_sizes, int n_in,
                              void* d_out, int out_size, void* d_ws, size_t ws_size,
                              hipStream_t stream) {
  const float* x  = (const float*)d_in[0];
  const float* wq = (const float*)d_in[1];
  const float* wk = (const float*)d_in[2];
  const float* wv = (const float*)d_in[3];
  char* ws = (char*)d_ws;

  // workspace layout (bytes) — identical to the passing rounds:
  //  [0,    768K)          Wt bf16 [3][128][1024]
  //  [768K, +2M)           Q  bf16 [8192][128]
  //  [768K+2M,  +2M)       K  bf16 [8192][128]
  //  [768K+4M,  +2M)       Vt bf16 [128][8192]
  //  [768K+6M,  +16M)      Op bf16 [<=8][8192][128]  (NSPLIT=4 uses first 8M)
  //  [768K+22M, +256K)     Mb f32
  //  [768K+22M+256K,+256K) Lb f32
  const size_t MB = (size_t)1 << 20;
  u16*   Wt = (u16*)(ws);
  u16*   Q  = (u16*)(ws + 768 * 1024);
  u16*   K  = (u16*)(ws + 768 * 1024 + 2 * MB);
  u16*   Vt = (u16*)(ws + 768 * 1024 + 4 * MB);
  u16*   Op = (u16*)(ws + 768 * 1024 + 6 * MB);
  float* Mb = (float*)(ws + 768 * 1024 + 22 * MB);
  float* Lb = (float*)(ws + 768 * 1024 + 22 * MB + 256 * 1024);
  float* out = (float*)d_out;

  k_wtrans<<<dim3((DIN * DOUT) / 256, 3), 256, 0, stream>>>(wq, wk, wv, Wt);
  k_qkv<<<dim3(SEQ / 16), 512, 0, stream>>>(x, Wt, Q, K, Vt);
  k_attn<<<dim3(SEQ / 64, NSPLIT), 256, 0, stream>>>(Q, K, Vt, Op, Mb, Lb);
  k_combine<<<dim3((SEQ * DOUT) / 256), 256, 0, stream>>>(Op, Mb, Lb, out);
}

// Round 6
// 154.321 us; speedup vs baseline: 2.5608x; 1.1673x over previous
//
#include <hip/hip_runtime.h>
#include <cstdint>

#define SEQ    8192
#define DIN    1024
#define DOUT   128
#define NSPLIT 4
#define KVTILE 64
// Q is pre-scaled by 1/sqrt(128) * log2(e) at the QKV GEMM epilogue, so the
// attn kernel works entirely in log2-units (exp2, no LOG2E muls).
#define QK_SCALE 0.1275174246f
#define RESCALE_THR 8.0f

typedef unsigned short u16;
typedef __bf16 bf16x8 __attribute__((ext_vector_type(8)));
typedef float  f32x4  __attribute__((ext_vector_type(4)));
typedef unsigned short u16x8 __attribute__((ext_vector_type(8)));
typedef unsigned short u16x4 __attribute__((ext_vector_type(4)));

// f32 -> bf16 via native cast (compiler emits v_cvt_pk_bf16_f32, RNE)
__device__ __forceinline__ u16 bfc(float f) {
  return __builtin_bit_cast(u16, (__bf16)f);
}
__device__ __forceinline__ float bf2f(u16 u) {
  union { uint32_t u; float f; } c; c.u = ((uint32_t)u) << 16; return c.f;
}

__device__ __forceinline__ bf16x8 ldsu8(const u16* base, int byteoff) {
  return __builtin_bit_cast(bf16x8,
    *reinterpret_cast<const u16x8*>(reinterpret_cast<const char*>(base) + byteoff));
}
__device__ __forceinline__ bf16x8 glbu8(const u16* p) {
  return __builtin_bit_cast(bf16x8, *reinterpret_cast<const u16x8*>(p));
}

// async global->LDS DMA, 16B per lane; LDS dest = base + lane*16 (linear).
__device__ __forceinline__ void gload_lds16(const void* g, void* l) {
  __builtin_amdgcn_global_load_lds(
      (const __attribute__((address_space(1))) void*)g,
      (__attribute__((address_space(3))) void*)l, 16, 0, 0);
}

// ---------------------------------------------------------------- kernel 0
// W [1024][128] fp32  ->  Wt [3][128][1024] bf16 (transposed)
__global__ __launch_bounds__(256) void k_wtrans(const float* __restrict__ wq,
                                                const float* __restrict__ wk,
                                                const float* __restrict__ wv,
                                                u16* __restrict__ Wt) {
  const float* w = (blockIdx.y == 0) ? wq : (blockIdx.y == 1) ? wk : wv;
  int idx = blockIdx.x * 256 + threadIdx.x;      // over DIN*DOUT
  int k = idx >> 7, n = idx & 127;
  Wt[(size_t)blockIdx.y * (DOUT * DIN) + (size_t)n * DIN + k] = bfc(w[idx]);
}

// ---------------------------------------------------------------- kernel 1
// Fused GEMM C[8192][384] = X[8192][1024] * [Wq|Wk|Wv].  (round-4 version)
// No LDS/barriers; 512 thr (8 waves); M-tile 16; wave owns 16 rows x 48 cols;
// grid 512 -> 16 waves/CU.  Q output pre-scaled by QK_SCALE.
__global__ __launch_bounds__(512) void k_qkv(const float* __restrict__ x,
                                             const u16* __restrict__ Wt,
                                             u16* __restrict__ Q,
                                             u16* __restrict__ K,
                                             u16* __restrict__ Vt) {
  const int tid  = threadIdx.x;
  const int lane = tid & 63, wave = tid >> 6;
  const int lm   = lane & 15, g = lane >> 4;
  const int nr   = wave * 48;          // n-range base (48 cols per wave)
  const int m0   = blockIdx.x * 16;
  const int mrow = m0 + lm;
  const float* xp = x + (size_t)mrow * DIN + 8 * g;

  f32x4 acc[3];
#pragma unroll
  for (int nb = 0; nb < 3; ++nb) acc[nb] = (f32x4){0.f, 0.f, 0.f, 0.f};

  for (int kc = 0; kc < DIN / 64; ++kc) {
    bf16x8 a[2];
#pragma unroll
    for (int t = 0; t < 2; ++t) {
      const float* p = xp + kc * 64 + t * 32;
      float4 lo = *reinterpret_cast<const float4*>(p);
      float4 hi = *reinterpret_cast<const float4*>(p + 4);
      u16x8 v = { bfc(lo.x), bfc(lo.y), bfc(lo.z), bfc(lo.w),
                  bfc(hi.x), bfc(hi.y), bfc(hi.z), bfc(hi.w) };
      a[t] = __builtin_bit_cast(bf16x8, v);
    }
#pragma unroll
    for (int nb = 0; nb < 3; ++nb) {
      const u16* wp = Wt + (size_t)(nr + nb * 16 + lm) * DIN + kc * 64 + 8 * g;
#pragma unroll
      for (int t = 0; t < 2; ++t) {
        bf16x8 b = glbu8(wp + t * 32);
        acc[nb] = __builtin_amdgcn_mfma_f32_16x16x32_bf16(a[t], b, acc[nb], 0, 0, 0);
      }
    }
  }

  // epilogue: C/D layout col=lane&15, row=(lane>>4)*4+reg  [HW-verified]
#pragma unroll
  for (int nb = 0; nb < 3; ++nb) {
    int n = nr + nb * 16 + lm;
    int which = n >> 7, col = n & 127;   // uniform per n-block
#pragma unroll
    for (int r = 0; r < 4; ++r) {
      int m = m0 + g * 4 + r;
      if (which == 0)       Q[(size_t)m * DOUT + col] = bfc(acc[nb][r] * QK_SCALE);
      else if (which == 1)  K[(size_t)m * DOUT + col] = bfc(acc[nb][r]);
      else                  Vt[(size_t)col * SEQ + m] = bfc(acc[nb][r]);
    }
  }
}

// ---------------------------------------------------------------- kernel 2
// Flash attention partials.  Round-5 staging/pipeline (gload_lds dbuf, one
// vmcnt(0)+barrier per iter) + SWAPPED-OPERAND QK^T (zero-cost: identical
// LDS reads, operands reversed) so each lane owns ONE q-row:
//   S^T tile: lane(lm,g) holds S[q0+lm][kv0 + cb*16 + g*4 + r]  (16 vals)
//   -> row max/sum: in-lane tree + 2 shuffles (xor16,32); m,l scalars
//   -> P-write: 4x ds_write_b64 (was 16x b16)
//   PV: O^T = mfma(V^T_frag, P_frag); lane holds O[q=lm][d=nb*16+g*4+r].
// All in log2-units (Q pre-scaled by QK_SCALE).
__global__ __launch_bounds__(256) void k_attn(const u16* __restrict__ Q,
                                              const u16* __restrict__ K,
                                              const u16* __restrict__ Vt,
                                              u16* __restrict__ Op,
                                              float* __restrict__ Mb,
                                              float* __restrict__ Lb) {
  __shared__ __attribute__((aligned(16))) u16 Ks[2][64 * 128];    // 2x16 KB
  __shared__ __attribute__((aligned(16))) u16 Vts[2][128 * 64];   // 2x16 KB
  __shared__ __attribute__((aligned(16))) u16 Ps[4][16 * 64];     //   8 KB
  const int tid  = threadIdx.x;
  const int lane = tid & 63, wave = tid >> 6;
  const int lm   = lane & 15, g = lane >> 4;
  const int m0   = blockIdx.x * 64;
  const int split = blockIdx.y;
  const int kvbase = split * (SEQ / NSPLIT);
  const int NIT = (SEQ / NSPLIT) / KVTILE;

  // STAGE: wave w stages K rows [w*16,+16) and Vt rows [w*32,+32) via 4+4
  // global_load_lds (64 lanes x 16B = 1KB each). LDS linear; global source
  // pre-swizzled by ((row&7)<<4) (XOR involution; read side applies same).
  auto stage = [&](int buf, int kv0) {
#pragma unroll
    for (int i = 0; i < 4; ++i) {
      int krow = wave * 16 + i * 4 + (lane >> 4);
      const char* gk = (const char*)K + ((size_t)(kv0 + krow) << 8) +
                       ((((lane & 15) << 4)) ^ ((krow & 7) << 4));
      gload_lds16(gk, &Ks[buf][wave * 2048 + i * 512]);
      int vrow = wave * 32 + i * 8 + (lane >> 3);
      const char* gv = (const char*)Vt + (size_t)vrow * (SEQ * 2) +
                       (size_t)kv0 * 2 +
                       ((((lane & 7) << 4)) ^ ((vrow & 7) << 4));
      gload_lds16(gv, &Vts[buf][wave * 2048 + i * 512]);
    }
  };

  bf16x8 qf[4];
  stage(0, kvbase);
  {
    const u16* qp = Q + (size_t)(m0 + wave * 16 + lm) * DOUT + 8 * g;
#pragma unroll
    for (int t = 0; t < 4; ++t) qf[t] = glbu8(qp + t * 32);
  }
  asm volatile("s_waitcnt vmcnt(0)" ::: "memory");
  __syncthreads();

  f32x4 o[8];
#pragma unroll
  for (int nb = 0; nb < 8; ++nb) o[nb] = (f32x4){0.f, 0.f, 0.f, 0.f};
  float mr = -1e30f, lr = 0.f;   // scalars: lane owns one q-row

  u16* pw = Ps[wave];
  char* pwb = reinterpret_cast<char*>(pw) + lm * 128;
  const int pswz = (lm & 7) << 4;
  int cur = 0;

  for (int it = 0; it < NIT; ++it) {
    if (it + 1 < NIT) stage(cur ^ 1, kvbase + (it + 1) * KVTILE);

    const u16* ks = Ks[cur];
    const u16* vs = Vts[cur];

    // ---- S^T = K Q^T  (swapped operands; reads identical to before)
    f32x4 s[4];
#pragma unroll
    for (int cb = 0; cb < 4; ++cb) {
      f32x4 a = (f32x4){0.f, 0.f, 0.f, 0.f};
      int krow = cb * 16 + lm;
#pragma unroll
      for (int t = 0; t < 4; ++t) {
        bf16x8 b = ldsu8(ks, krow * 256 +
                             (((t * 32 + 8 * g) * 2) ^ ((krow & 7) << 4)));
        a = __builtin_amdgcn_mfma_f32_16x16x32_bf16(b, qf[t], a, 0, 0, 0);
      }
      s[cb] = a;            // already in log2-units (Q pre-scaled)
    }

    // ---- softmax for this lane's q-row: in-lane tree + 2 shuffles
    float c0 = fmaxf(fmaxf(s[0][0], s[0][1]), fmaxf(s[0][2], s[0][3]));
    float c1 = fmaxf(fmaxf(s[1][0], s[1][1]), fmaxf(s[1][2], s[1][3]));
    float c2 = fmaxf(fmaxf(s[2][0], s[2][1]), fmaxf(s[2][2], s[2][3]));
    float c3 = fmaxf(fmaxf(s[3][0], s[3][1]), fmaxf(s[3][2], s[3][3]));
    float rm = fmaxf(fmaxf(c0, c1), fmaxf(c2, c3));
    rm = fmaxf(rm, __shfl_xor(rm, 16));
    rm = fmaxf(rm, __shfl_xor(rm, 32));

    if (__any(rm - mr > RESCALE_THR)) {   // first tile + rare growth
      float mn = fmaxf(mr, rm);
      float alpha = exp2f(mr - mn);
      mr = mn;
      lr *= alpha;
#pragma unroll
      for (int nb = 0; nb < 8; ++nb) o[nb] *= alpha;
    }

    // ---- P = exp2(S - m), bounded by 2^THR; write b64 per cb, sum tree
    float rsum = 0.f;
#pragma unroll
    for (int cb = 0; cb < 4; ++cb) {
      float p0 = exp2f(s[cb][0] - mr);
      float p1 = exp2f(s[cb][1] - mr);
      float p2 = exp2f(s[cb][2] - mr);
      float p3 = exp2f(s[cb][3] - mr);
      u16x4 w = { bfc(p0), bfc(p1), bfc(p2), bfc(p3) };
      *reinterpret_cast<u16x4*>(pwb + ((cb * 32 + g * 8) ^ pswz)) = w;
      rsum += (p0 + p1) + (p2 + p3);
    }
    rsum += __shfl_xor(rsum, 16);
    rsum += __shfl_xor(rsum, 32);
    lr += rsum;

    // order P writes before P reads (per-wave DS in-order; rule-18 fence)
    asm volatile("s_waitcnt lgkmcnt(0)" ::: "memory");
    __builtin_amdgcn_sched_barrier(0);

    // ---- O^T += V^T P  (A = V^T rows = d, B = P cols = q)
#pragma unroll
    for (int t = 0; t < 2; ++t) {
      bf16x8 pb = ldsu8(pw, lm * 128 + ((t * 64 + g * 16) ^ pswz));
#pragma unroll
      for (int nb = 0; nb < 8; ++nb) {
        int vrow = nb * 16 + lm;
        bf16x8 vb = ldsu8(vs, vrow * 128 +
                              (((t * 32 + 8 * g) * 2) ^ ((vrow & 7) << 4)));
        o[nb] = __builtin_amdgcn_mfma_f32_16x16x32_bf16(vb, pb, o[nb], 0, 0, 0);
      }
    }

    asm volatile("s_waitcnt vmcnt(0)" ::: "memory");
    __syncthreads();
    cur ^= 1;
  }

  // ---- store partials: lane holds O[q=m0+wave*16+lm][d=nb*16+g*4+r]
  const size_t ob = (size_t)split * SEQ * DOUT;
  const int m = m0 + wave * 16 + lm;
#pragma unroll
  for (int nb = 0; nb < 8; ++nb) {
    u16x4 w = { bfc(o[nb][0]), bfc(o[nb][1]), bfc(o[nb][2]), bfc(o[nb][3]) };
    *reinterpret_cast<u16x4*>(Op + ob + (size_t)m * DOUT + nb * 16 + g * 4) = w;
  }
  if (g == 0) {
    Mb[split * SEQ + m] = mr;   // log2-units
    Lb[split * SEQ + m] = lr;
  }
}

// ---------------------------------------------------------------- kernel 3
// combine in log2-units (Mb already scaled; plain exp2)
__global__ __launch_bounds__(256) void k_combine(const u16* __restrict__ Op,
                                                 const float* __restrict__ Mb,
                                                 const float* __restrict__ Lb,
                                                 float* __restrict__ out) {
  int idx = blockIdx.x * 256 + threadIdx.x;   // over SEQ*DOUT
  int srow = idx >> 7;
  float M = -1e30f;
#pragma unroll
  for (int s = 0; s < NSPLIT; ++s) M = fmaxf(M, Mb[s * SEQ + srow]);
  float num = 0.f, den = 0.f;
  const size_t st = (size_t)SEQ * DOUT;
#pragma unroll
  for (int s = 0; s < NSPLIT; ++s) {
    float e = exp2f(Mb[s * SEQ + srow] - M);
    den += Lb[s * SEQ + srow] * e;
    num += bf2f(Op[s * st + idx]) * e;
  }
  out[idx] = num / den;
}

// ---------------------------------------------------------------- launch
extern "C" void kernel_launch(void* const* d_in, const int* in_sizes, int n_in,
                              void* d_out, int out_size, void* d_ws, size_t ws_size,
                              hipStream_t stream) {
  const float* x  = (const float*)d_in[0];
  const float* wq = (const float*)d_in[1];
  const float* wk = (const float*)d_in[2];
  const float* wv = (const float*)d_in[3];
  char* ws = (char*)d_ws;

  // workspace layout (bytes) — identical to the passing rounds:
  //  [0,    768K)          Wt bf16 [3][128][1024]
  //  [768K, +2M)           Q  bf16 [8192][128]   (pre-scaled by QK_SCALE)
  //  [768K+2M,  +2M)       K  bf16 [8192][128]
  //  [768K+4M,  +2M)       Vt bf16 [128][8192]
  //  [768K+6M,  +16M)      Op bf16 [<=8][8192][128]  (NSPLIT=4 uses first 8M)
  //  [768K+22M, +256K)     Mb f32
  //  [768K+22M+256K,+256K) Lb f32
  const size_t MB = (size_t)1 << 20;
  u16*   Wt = (u16*)(ws);
  u16*   Q  = (u16*)(ws + 768 * 1024);
  u16*   K  = (u16*)(ws + 768 * 1024 + 2 * MB);
  u16*   Vt = (u16*)(ws + 768 * 1024 + 4 * MB);
  u16*   Op = (u16*)(ws + 768 * 1024 + 6 * MB);
  float* Mb = (float*)(ws + 768 * 1024 + 22 * MB);
  float* Lb = (float*)(ws + 768 * 1024 + 22 * MB + 256 * 1024);
  float* out = (float*)d_out;

  k_wtrans<<<dim3((DIN * DOUT) / 256, 3), 256, 0, stream>>>(wq, wk, wv, Wt);
  k_qkv<<<dim3(SEQ / 16), 512, 0, stream>>>(x, Wt, Q, K, Vt);
  k_attn<<<dim3(SEQ / 64, NSPLIT), 256, 0, stream>>>(Q, K, Vt, Op, Mb, Lb);
  k_combine<<<dim3((SEQ * DOUT) / 256), 256, 0, stream>>>(Op, Mb, Lb, out);
}

// Round 7
// 103.497 us; speedup vs baseline: 3.8183x; 1.4911x over previous
//
#include <hip/hip_runtime.h>
#include <cstdint>

#define SEQ    8192
#define DIN    1024
#define DOUT   128
#define NSPLIT 4
#define KVTILE 64
// Q is pre-scaled by 1/sqrt(128) * log2(e) at the QKV GEMM epilogue, so the
// attn kernel works entirely in log2-units (exp2, no LOG2E muls).
#define QK_SCALE 0.1275174246f
#define RESCALE_THR 8.0f

typedef unsigned short u16;
typedef __bf16 bf16x8 __attribute__((ext_vector_type(8)));
typedef float  f32x4  __attribute__((ext_vector_type(4)));
typedef unsigned short u16x8 __attribute__((ext_vector_type(8)));
typedef unsigned short u16x4 __attribute__((ext_vector_type(4)));

// f32 -> bf16 via native cast (compiler emits v_cvt_pk_bf16_f32, RNE)
__device__ __forceinline__ u16 bfc(float f) {
  return __builtin_bit_cast(u16, (__bf16)f);
}
__device__ __forceinline__ float bf2f(u16 u) {
  union { uint32_t u; float f; } c; c.u = ((uint32_t)u) << 16; return c.f;
}

__device__ __forceinline__ bf16x8 ldsu8(const u16* base, int byteoff) {
  return __builtin_bit_cast(bf16x8,
    *reinterpret_cast<const u16x8*>(reinterpret_cast<const char*>(base) + byteoff));
}
__device__ __forceinline__ bf16x8 glbu8(const u16* p) {
  return __builtin_bit_cast(bf16x8, *reinterpret_cast<const u16x8*>(p));
}

// async global->LDS DMA, 16B per lane; LDS dest = wave-uniform base + lane*16.
__device__ __forceinline__ void gload_lds16(const void* g, void* l) {
  __builtin_amdgcn_global_load_lds(
      (const __attribute__((address_space(1))) void*)g,
      (__attribute__((address_space(3))) void*)l, 16, 0, 0);
}

// ---------------------------------------------------------------- kernel 0
// W [1024][128] fp32  ->  Wt [3][128][1024] bf16 (transposed)
__global__ __launch_bounds__(256) void k_wtrans(const float* __restrict__ wq,
                                                const float* __restrict__ wk,
                                                const float* __restrict__ wv,
                                                u16* __restrict__ Wt) {
  const float* w = (blockIdx.y == 0) ? wq : (blockIdx.y == 1) ? wk : wv;
  int idx = blockIdx.x * 256 + threadIdx.x;      // over DIN*DOUT
  int k = idx >> 7, n = idx & 127;
  Wt[(size_t)blockIdx.y * (DOUT * DIN) + (size_t)n * DIN + k] = bfc(w[idx]);
}

// ---------------------------------------------------------------- kernel 0b
// X fp32 [8192][1024] -> Xb bf16 [8192][1024], coalesced. 8 elems/thread.
__global__ __launch_bounds__(256) void k_xcast(const float* __restrict__ x,
                                               u16* __restrict__ Xb) {
  size_t base = ((size_t)blockIdx.x * 256 + threadIdx.x) * 8;
  float4 lo = *reinterpret_cast<const float4*>(x + base);
  float4 hi = *reinterpret_cast<const float4*>(x + base + 4);
  u16x8 v = { bfc(lo.x), bfc(lo.y), bfc(lo.z), bfc(lo.w),
              bfc(hi.x), bfc(hi.y), bfc(hi.z), bfc(hi.w) };
  *reinterpret_cast<u16x8*>(Xb + base) = v;
}

// ---------------------------------------------------------------- kernel 1
// GEMM C[8192][384] = Xb[8192][1024] * Wt^T  (Wt [384][1024] row-major).
// m97-style: M-tile 64 x N-tile 96 x BK 128; both operands gload_lds-staged
// (swizzle on global source, linear LDS, swizzled ds_read_b128); double-
// buffered, one vmcnt(0)+barrier per k-step. Block 256 thr (4 waves = 2x2),
// wave = 32 rows x 48 cols. Grid (128,4) = 512 blocks = 2/CU. LDS 80 KB.
__global__ __launch_bounds__(256, 2) void k_gemm(const u16* __restrict__ Xb,
                                                 const u16* __restrict__ Wt,
                                                 u16* __restrict__ Q,
                                                 u16* __restrict__ K,
                                                 u16* __restrict__ Vt) {
  __shared__ __attribute__((aligned(16))) u16 As[2][64 * 128];   // 2x16 KB
  __shared__ __attribute__((aligned(16))) u16 Bs[2][96 * 128];   // 2x24 KB
  const int tid  = threadIdx.x;
  const int lane = tid & 63, wave = tid >> 6;
  const int lm   = lane & 15, g = lane >> 4;
  const int wm   = wave >> 1, wn = wave & 1;     // 2x2 wave grid
  const int m0   = blockIdx.x * 64;
  const int n0   = blockIdx.y * 96;
  const int swzr = (lm & 7) << 4;

  // staging geometry: thread covers row (i*16 + tid>>4), col-bytes (tid&15)*16
  // of the [rows][256B] tile; source col pre-swizzled by ((row&7)<<4).
  const int trow = tid >> 4;                     // 0..15
  const int tswz = ((tid & 15) << 4) ^ ((trow & 7) << 4);
  const char* baseA = (const char*)Xb + (size_t)(m0 + trow) * 2048 + tswz;
  const char* baseB = (const char*)Wt + (size_t)(n0 + trow) * 2048 + tswz;

  auto stage = [&](int buf, int kc) {
    const int kb = kc * 256;                     // 128 k * 2B
#pragma unroll
    for (int i = 0; i < 4; ++i)                  // A: 64 rows = 4 issues
      gload_lds16(baseA + kb + i * 32768, &As[buf][i * 2048 + wave * 512]);
#pragma unroll
    for (int j = 0; j < 6; ++j)                  // B: 96 rows = 6 issues
      gload_lds16(baseB + kb + j * 32768, &Bs[buf][j * 2048 + wave * 512]);
  };

  f32x4 acc[2][3];
#pragma unroll
  for (int s = 0; s < 2; ++s)
#pragma unroll
    for (int nb = 0; nb < 3; ++nb) acc[s][nb] = (f32x4){0.f, 0.f, 0.f, 0.f};

  auto compute = [&](int buf) {
    const u16* As_ = As[buf];
    const u16* Bs_ = Bs[buf];
    bf16x8 a[2][4], b[3][4];
#pragma unroll
    for (int s = 0; s < 2; ++s)
#pragma unroll
      for (int t = 0; t < 4; ++t)
        a[s][t] = ldsu8(As_, (wm * 32 + s * 16 + lm) * 256 +
                             ((t * 64 + 16 * g) ^ swzr));
#pragma unroll
    for (int nb = 0; nb < 3; ++nb)
#pragma unroll
      for (int t = 0; t < 4; ++t)
        b[nb][t] = ldsu8(Bs_, (wn * 48 + nb * 16 + lm) * 256 +
                              ((t * 64 + 16 * g) ^ swzr));
#pragma unroll
    for (int s = 0; s < 2; ++s)
#pragma unroll
      for (int nb = 0; nb < 3; ++nb)
#pragma unroll
        for (int t = 0; t < 4; ++t)
          acc[s][nb] = __builtin_amdgcn_mfma_f32_16x16x32_bf16(
              a[s][t], b[nb][t], acc[s][nb], 0, 0, 0);
  };

  stage(0, 0);
  asm volatile("s_waitcnt vmcnt(0)" ::: "memory");
  __syncthreads();

#pragma unroll
  for (int kc = 0; kc < 8; kc += 2) {
    if (kc + 1 < 8) stage(1, kc + 1);
    compute(0);
    asm volatile("s_waitcnt vmcnt(0)" ::: "memory");
    __syncthreads();
    if (kc + 2 < 8) stage(0, kc + 2);
    compute(1);
    asm volatile("s_waitcnt vmcnt(0)" ::: "memory");
    __syncthreads();
  }

  // epilogue: C/D layout col=lane&15, row=(lane>>4)*4+reg  [HW-verified]
#pragma unroll
  for (int s = 0; s < 2; ++s)
#pragma unroll
    for (int nb = 0; nb < 3; ++nb) {
      int n = n0 + wn * 48 + nb * 16 + lm;
      int which = n >> 7, col = n & 127;         // uniform per nb
#pragma unroll
      for (int r = 0; r < 4; ++r) {
        int m = m0 + wm * 32 + s * 16 + g * 4 + r;
        if (which == 0)       Q[(size_t)m * DOUT + col] = bfc(acc[s][nb][r] * QK_SCALE);
        else if (which == 1)  K[(size_t)m * DOUT + col] = bfc(acc[s][nb][r]);
        else                  Vt[(size_t)col * SEQ + m] = bfc(acc[s][nb][r]);
      }
    }
}

// ---------------------------------------------------------------- kernel 2
// Flash attention partials.  (byte-identical to round 6)
__global__ __launch_bounds__(256) void k_attn(const u16* __restrict__ Q,
                                              const u16* __restrict__ K,
                                              const u16* __restrict__ Vt,
                                              u16* __restrict__ Op,
                                              float* __restrict__ Mb,
                                              float* __restrict__ Lb) {
  __shared__ __attribute__((aligned(16))) u16 Ks[2][64 * 128];    // 2x16 KB
  __shared__ __attribute__((aligned(16))) u16 Vts[2][128 * 64];   // 2x16 KB
  __shared__ __attribute__((aligned(16))) u16 Ps[4][16 * 64];     //   8 KB
  const int tid  = threadIdx.x;
  const int lane = tid & 63, wave = tid >> 6;
  const int lm   = lane & 15, g = lane >> 4;
  const int m0   = blockIdx.x * 64;
  const int split = blockIdx.y;
  const int kvbase = split * (SEQ / NSPLIT);
  const int NIT = (SEQ / NSPLIT) / KVTILE;

  auto stage = [&](int buf, int kv0) {
#pragma unroll
    for (int i = 0; i < 4; ++i) {
      int krow = wave * 16 + i * 4 + (lane >> 4);
      const char* gk = (const char*)K + ((size_t)(kv0 + krow) << 8) +
                       ((((lane & 15) << 4)) ^ ((krow & 7) << 4));
      gload_lds16(gk, &Ks[buf][wave * 2048 + i * 512]);
      int vrow = wave * 32 + i * 8 + (lane >> 3);
      const char* gv = (const char*)Vt + (size_t)vrow * (SEQ * 2) +
                       (size_t)kv0 * 2 +
                       ((((lane & 7) << 4)) ^ ((vrow & 7) << 4));
      gload_lds16(gv, &Vts[buf][wave * 2048 + i * 512]);
    }
  };

  bf16x8 qf[4];
  stage(0, kvbase);
  {
    const u16* qp = Q + (size_t)(m0 + wave * 16 + lm) * DOUT + 8 * g;
#pragma unroll
    for (int t = 0; t < 4; ++t) qf[t] = glbu8(qp + t * 32);
  }
  asm volatile("s_waitcnt vmcnt(0)" ::: "memory");
  __syncthreads();

  f32x4 o[8];
#pragma unroll
  for (int nb = 0; nb < 8; ++nb) o[nb] = (f32x4){0.f, 0.f, 0.f, 0.f};
  float mr = -1e30f, lr = 0.f;   // scalars: lane owns one q-row

  u16* pw = Ps[wave];
  char* pwb = reinterpret_cast<char*>(pw) + lm * 128;
  const int pswz = (lm & 7) << 4;
  int cur = 0;

  for (int it = 0; it < NIT; ++it) {
    if (it + 1 < NIT) stage(cur ^ 1, kvbase + (it + 1) * KVTILE);

    const u16* ks = Ks[cur];
    const u16* vs = Vts[cur];

    // ---- S^T = K Q^T  (swapped operands)
    f32x4 s[4];
#pragma unroll
    for (int cb = 0; cb < 4; ++cb) {
      f32x4 a = (f32x4){0.f, 0.f, 0.f, 0.f};
      int krow = cb * 16 + lm;
#pragma unroll
      for (int t = 0; t < 4; ++t) {
        bf16x8 b = ldsu8(ks, krow * 256 +
                             (((t * 32 + 8 * g) * 2) ^ ((krow & 7) << 4)));
        a = __builtin_amdgcn_mfma_f32_16x16x32_bf16(b, qf[t], a, 0, 0, 0);
      }
      s[cb] = a;            // log2-units (Q pre-scaled)
    }

    // ---- softmax for this lane's q-row: in-lane tree + 2 shuffles
    float c0 = fmaxf(fmaxf(s[0][0], s[0][1]), fmaxf(s[0][2], s[0][3]));
    float c1 = fmaxf(fmaxf(s[1][0], s[1][1]), fmaxf(s[1][2], s[1][3]));
    float c2 = fmaxf(fmaxf(s[2][0], s[2][1]), fmaxf(s[2][2], s[2][3]));
    float c3 = fmaxf(fmaxf(s[3][0], s[3][1]), fmaxf(s[3][2], s[3][3]));
    float rm = fmaxf(fmaxf(c0, c1), fmaxf(c2, c3));
    rm = fmaxf(rm, __shfl_xor(rm, 16));
    rm = fmaxf(rm, __shfl_xor(rm, 32));

    if (__any(rm - mr > RESCALE_THR)) {   // first tile + rare growth
      float mn = fmaxf(mr, rm);
      float alpha = exp2f(mr - mn);
      mr = mn;
      lr *= alpha;
#pragma unroll
      for (int nb = 0; nb < 8; ++nb) o[nb] *= alpha;
    }

    // ---- P = exp2(S - m); write b64 per cb, sum tree
    float rsum = 0.f;
#pragma unroll
    for (int cb = 0; cb < 4; ++cb) {
      float p0 = exp2f(s[cb][0] - mr);
      float p1 = exp2f(s[cb][1] - mr);
      float p2 = exp2f(s[cb][2] - mr);
      float p3 = exp2f(s[cb][3] - mr);
      u16x4 w = { bfc(p0), bfc(p1), bfc(p2), bfc(p3) };
      *reinterpret_cast<u16x4*>(pwb + ((cb * 32 + g * 8) ^ pswz)) = w;
      rsum += (p0 + p1) + (p2 + p3);
    }
    rsum += __shfl_xor(rsum, 16);
    rsum += __shfl_xor(rsum, 32);
    lr += rsum;

    asm volatile("s_waitcnt lgkmcnt(0)" ::: "memory");
    __builtin_amdgcn_sched_barrier(0);

    // ---- O^T += V^T P
#pragma unroll
    for (int t = 0; t < 2; ++t) {
      bf16x8 pb = ldsu8(pw, lm * 128 + ((t * 64 + g * 16) ^ pswz));
#pragma unroll
      for (int nb = 0; nb < 8; ++nb) {
        int vrow = nb * 16 + lm;
        bf16x8 vb = ldsu8(vs, vrow * 128 +
                              (((t * 32 + 8 * g) * 2) ^ ((vrow & 7) << 4)));
        o[nb] = __builtin_amdgcn_mfma_f32_16x16x32_bf16(vb, pb, o[nb], 0, 0, 0);
      }
    }

    asm volatile("s_waitcnt vmcnt(0)" ::: "memory");
    __syncthreads();
    cur ^= 1;
  }

  // ---- store partials: lane holds O[q=m0+wave*16+lm][d=nb*16+g*4+r]
  const size_t ob = (size_t)split * SEQ * DOUT;
  const int m = m0 + wave * 16 + lm;
#pragma unroll
  for (int nb = 0; nb < 8; ++nb) {
    u16x4 w = { bfc(o[nb][0]), bfc(o[nb][1]), bfc(o[nb][2]), bfc(o[nb][3]) };
    *reinterpret_cast<u16x4*>(Op + ob + (size_t)m * DOUT + nb * 16 + g * 4) = w;
  }
  if (g == 0) {
    Mb[split * SEQ + m] = mr;   // log2-units
    Lb[split * SEQ + m] = lr;
  }
}

// ---------------------------------------------------------------- kernel 3
__global__ __launch_bounds__(256) void k_combine(const u16* __restrict__ Op,
                                                 const float* __restrict__ Mb,
                                                 const float* __restrict__ Lb,
                                                 float* __restrict__ out) {
  int idx = blockIdx.x * 256 + threadIdx.x;   // over SEQ*DOUT
  int srow = idx >> 7;
  float M = -1e30f;
#pragma unroll
  for (int s = 0; s < NSPLIT; ++s) M = fmaxf(M, Mb[s * SEQ + srow]);
  float num = 0.f, den = 0.f;
  const size_t st = (size_t)SEQ * DOUT;
#pragma unroll
  for (int s = 0; s < NSPLIT; ++s) {
    float e = exp2f(Mb[s * SEQ + srow] - M);
    den += Lb[s * SEQ + srow] * e;
    num += bf2f(Op[s * st + idx]) * e;
  }
  out[idx] = num / den;
}

// ---------------------------------------------------------------- launch
extern "C" void kernel_launch(void* const* d_in, const int* in_sizes, int n_in,
                              void* d_out, int out_size, void* d_ws, size_t ws_size,
                              hipStream_t stream) {
  const float* x  = (const float*)d_in[0];
  const float* wq = (const float*)d_in[1];
  const float* wk = (const float*)d_in[2];
  const float* wv = (const float*)d_in[3];
  char* ws = (char*)d_ws;

  // workspace layout (bytes), total 23.25 MiB (same proven footprint):
  //  [0,    768K)          Wt bf16 [3][128][1024]
  //  [768K, +2M)           Q  bf16 [8192][128]   (pre-scaled by QK_SCALE)
  //  [768K+2M,  +2M)       K  bf16 [8192][128]
  //  [768K+4M,  +2M)       Vt bf16 [128][8192]
  //  [7M,   +16M)          Xb bf16 [8192][1024]  ALIASED with
  //                        Op bf16 [4][8192][128] (Xb dead before k_attn)
  //  [23M,  +128K)         Mb f32 [4][8192]
  //  [23M+128K, +128K)     Lb f32 [4][8192]
  const size_t MB = (size_t)1 << 20;
  u16*   Wt = (u16*)(ws);
  u16*   Q  = (u16*)(ws + 768 * 1024);
  u16*   K  = (u16*)(ws + 768 * 1024 + 2 * MB);
  u16*   Vt = (u16*)(ws + 768 * 1024 + 4 * MB);
  u16*   Xb = (u16*)(ws + 7 * MB);
  u16*   Op = (u16*)(ws + 7 * MB);
  float* Mb = (float*)(ws + 23 * MB);
  float* Lb = (float*)(ws + 23 * MB + 128 * 1024);
  float* out = (float*)d_out;

  k_wtrans<<<dim3((DIN * DOUT) / 256, 3), 256, 0, stream>>>(wq, wk, wv, Wt);
  k_xcast<<<dim3((SEQ * DIN) / (256 * 8)), 256, 0, stream>>>(x, Xb);
  k_gemm<<<dim3(SEQ / 64, 4), 256, 0, stream>>>(Xb, Wt, Q, K, Vt);
  k_attn<<<dim3(SEQ / 64, NSPLIT), 256, 0, stream>>>(Q, K, Vt, Op, Mb, Lb);
  k_combine<<<dim3((SEQ * DOUT) / 256), 256, 0, stream>>>(Op, Mb, Lb, out);
}

// Round 8
// 92.227 us; speedup vs baseline: 4.2849x; 1.1222x over previous
//
#include <hip/hip_runtime.h>
#include <cstdint>

#define SEQ    8192
#define DIN    1024
#define DOUT   128
#define NSPLIT 8
#define KVTILE 64
#define QTILE  128
// Q is pre-scaled by 1/sqrt(128) * log2(e) at the QKV GEMM epilogue, so the
// attn kernel works entirely in log2-units (exp2, no LOG2E muls).
#define QK_SCALE 0.1275174246f
#define RESCALE_THR 8.0f

typedef unsigned short u16;
typedef __bf16 bf16x8 __attribute__((ext_vector_type(8)));
typedef float  f32x4  __attribute__((ext_vector_type(4)));
typedef unsigned short u16x8 __attribute__((ext_vector_type(8)));
typedef unsigned short u16x4 __attribute__((ext_vector_type(4)));

// f32 -> bf16 via native cast (compiler emits v_cvt_pk_bf16_f32, RNE)
__device__ __forceinline__ u16 bfc(float f) {
  return __builtin_bit_cast(u16, (__bf16)f);
}
__device__ __forceinline__ float bf2f(u16 u) {
  union { uint32_t u; float f; } c; c.u = ((uint32_t)u) << 16; return c.f;
}

__device__ __forceinline__ bf16x8 ldsu8(const u16* base, int byteoff) {
  return __builtin_bit_cast(bf16x8,
    *reinterpret_cast<const u16x8*>(reinterpret_cast<const char*>(base) + byteoff));
}
__device__ __forceinline__ bf16x8 glbu8(const u16* p) {
  return __builtin_bit_cast(bf16x8, *reinterpret_cast<const u16x8*>(p));
}

// async global->LDS DMA, 16B per lane; LDS dest = wave-uniform base + lane*16.
__device__ __forceinline__ void gload_lds16(const void* g, void* l) {
  __builtin_amdgcn_global_load_lds(
      (const __attribute__((address_space(1))) void*)g,
      (__attribute__((address_space(3))) void*)l, 16, 0, 0);
}

// ---------------------------------------------------------------- kernel 0
// W [1024][128] fp32  ->  Wt [3][128][1024] bf16 (transposed)
__global__ __launch_bounds__(256) void k_wtrans(const float* __restrict__ wq,
                                                const float* __restrict__ wk,
                                                const float* __restrict__ wv,
                                                u16* __restrict__ Wt) {
  const float* w = (blockIdx.y == 0) ? wq : (blockIdx.y == 1) ? wk : wv;
  int idx = blockIdx.x * 256 + threadIdx.x;      // over DIN*DOUT
  int k = idx >> 7, n = idx & 127;
  Wt[(size_t)blockIdx.y * (DOUT * DIN) + (size_t)n * DIN + k] = bfc(w[idx]);
}

// ---------------------------------------------------------------- kernel 0b
// X fp32 [8192][1024] -> Xb bf16 [8192][1024], coalesced. 8 elems/thread.
__global__ __launch_bounds__(256) void k_xcast(const float* __restrict__ x,
                                               u16* __restrict__ Xb) {
  size_t base = ((size_t)blockIdx.x * 256 + threadIdx.x) * 8;
  float4 lo = *reinterpret_cast<const float4*>(x + base);
  float4 hi = *reinterpret_cast<const float4*>(x + base + 4);
  u16x8 v = { bfc(lo.x), bfc(lo.y), bfc(lo.z), bfc(lo.w),
              bfc(hi.x), bfc(hi.y), bfc(hi.z), bfc(hi.w) };
  *reinterpret_cast<u16x8*>(Xb + base) = v;
}

// ---------------------------------------------------------------- kernel 1
// GEMM C[8192][384] = Xb[8192][1024] * Wt^T.  (byte-identical to round 7)
__global__ __launch_bounds__(256, 2) void k_gemm(const u16* __restrict__ Xb,
                                                 const u16* __restrict__ Wt,
                                                 u16* __restrict__ Q,
                                                 u16* __restrict__ K,
                                                 u16* __restrict__ Vt) {
  __shared__ __attribute__((aligned(16))) u16 As[2][64 * 128];   // 2x16 KB
  __shared__ __attribute__((aligned(16))) u16 Bs[2][96 * 128];   // 2x24 KB
  const int tid  = threadIdx.x;
  const int lane = tid & 63, wave = tid >> 6;
  const int lm   = lane & 15, g = lane >> 4;
  const int wm   = wave >> 1, wn = wave & 1;     // 2x2 wave grid
  const int m0   = blockIdx.x * 64;
  const int n0   = blockIdx.y * 96;
  const int swzr = (lm & 7) << 4;

  const int trow = tid >> 4;                     // 0..15
  const int tswz = ((tid & 15) << 4) ^ ((trow & 7) << 4);
  const char* baseA = (const char*)Xb + (size_t)(m0 + trow) * 2048 + tswz;
  const char* baseB = (const char*)Wt + (size_t)(n0 + trow) * 2048 + tswz;

  auto stage = [&](int buf, int kc) {
    const int kb = kc * 256;                     // 128 k * 2B
#pragma unroll
    for (int i = 0; i < 4; ++i)                  // A: 64 rows = 4 issues
      gload_lds16(baseA + kb + i * 32768, &As[buf][i * 2048 + wave * 512]);
#pragma unroll
    for (int j = 0; j < 6; ++j)                  // B: 96 rows = 6 issues
      gload_lds16(baseB + kb + j * 32768, &Bs[buf][j * 2048 + wave * 512]);
  };

  f32x4 acc[2][3];
#pragma unroll
  for (int s = 0; s < 2; ++s)
#pragma unroll
    for (int nb = 0; nb < 3; ++nb) acc[s][nb] = (f32x4){0.f, 0.f, 0.f, 0.f};

  auto compute = [&](int buf) {
    const u16* As_ = As[buf];
    const u16* Bs_ = Bs[buf];
    bf16x8 a[2][4], b[3][4];
#pragma unroll
    for (int s = 0; s < 2; ++s)
#pragma unroll
      for (int t = 0; t < 4; ++t)
        a[s][t] = ldsu8(As_, (wm * 32 + s * 16 + lm) * 256 +
                             ((t * 64 + 16 * g) ^ swzr));
#pragma unroll
    for (int nb = 0; nb < 3; ++nb)
#pragma unroll
      for (int t = 0; t < 4; ++t)
        b[nb][t] = ldsu8(Bs_, (wn * 48 + nb * 16 + lm) * 256 +
                              ((t * 64 + 16 * g) ^ swzr));
#pragma unroll
    for (int s = 0; s < 2; ++s)
#pragma unroll
      for (int nb = 0; nb < 3; ++nb)
#pragma unroll
        for (int t = 0; t < 4; ++t)
          acc[s][nb] = __builtin_amdgcn_mfma_f32_16x16x32_bf16(
              a[s][t], b[nb][t], acc[s][nb], 0, 0, 0);
  };

  stage(0, 0);
  asm volatile("s_waitcnt vmcnt(0)" ::: "memory");
  __syncthreads();

#pragma unroll
  for (int kc = 0; kc < 8; kc += 2) {
    if (kc + 1 < 8) stage(1, kc + 1);
    compute(0);
    asm volatile("s_waitcnt vmcnt(0)" ::: "memory");
    __syncthreads();
    if (kc + 2 < 8) stage(0, kc + 2);
    compute(1);
    asm volatile("s_waitcnt vmcnt(0)" ::: "memory");
    __syncthreads();
  }

  // epilogue: C/D layout col=lane&15, row=(lane>>4)*4+reg  [HW-verified]
#pragma unroll
  for (int s = 0; s < 2; ++s)
#pragma unroll
    for (int nb = 0; nb < 3; ++nb) {
      int n = n0 + wn * 48 + nb * 16 + lm;
      int which = n >> 7, col = n & 127;         // uniform per nb
#pragma unroll
      for (int r = 0; r < 4; ++r) {
        int m = m0 + wm * 32 + s * 16 + g * 4 + r;
        if (which == 0)       Q[(size_t)m * DOUT + col] = bfc(acc[s][nb][r] * QK_SCALE);
        else if (which == 1)  K[(size_t)m * DOUT + col] = bfc(acc[s][nb][r]);
        else                  Vt[(size_t)col * SEQ + m] = bfc(acc[s][nb][r]);
      }
    }
}

// ---------------------------------------------------------------- kernel 2
// Flash attention partials.  Round-6 inner loop, Q-tile 128 (8 waves, 512
// thr): 8 waves share each K/V tile (staging per wave halves), grid
// (SEQ/128=64, NSPLIT=8) = 512 blocks = 2 blocks/CU = 16 waves/CU (50% occ
// ceiling, was 25%).  LDS 80 KB: Ks 2x16 + Vts 2x16 + Ps 8x2.
__global__ __launch_bounds__(512) void k_attn(const u16* __restrict__ Q,
                                              const u16* __restrict__ K,
                                              const u16* __restrict__ Vt,
                                              u16* __restrict__ Op,
                                              float* __restrict__ Mb,
                                              float* __restrict__ Lb) {
  __shared__ __attribute__((aligned(16))) u16 Ks[2][64 * 128];    // 2x16 KB
  __shared__ __attribute__((aligned(16))) u16 Vts[2][128 * 64];   // 2x16 KB
  __shared__ __attribute__((aligned(16))) u16 Ps[8][16 * 64];     //  16 KB
  const int tid  = threadIdx.x;
  const int lane = tid & 63, wave = tid >> 6;       // wave 0..7
  const int lm   = lane & 15, g = lane >> 4;
  const int m0   = blockIdx.x * QTILE;
  const int split = blockIdx.y;
  const int kvbase = split * (SEQ / NSPLIT);
  const int NIT = (SEQ / NSPLIT) / KVTILE;          // 16

  // STAGE: wave w stages K rows [w*8,+8) (2 issues) and Vt rows [w*16,+16)
  // (2 issues); each gload_lds = 64 lanes x 16B = 1KB. LDS linear; global
  // source pre-swizzled by ((row&7)<<4) (XOR involution, same on read).
  auto stage = [&](int buf, int kv0) {
#pragma unroll
    for (int i = 0; i < 2; ++i) {
      int krow = wave * 8 + i * 4 + (lane >> 4);
      const char* gk = (const char*)K + ((size_t)(kv0 + krow) << 8) +
                       ((((lane & 15) << 4)) ^ ((krow & 7) << 4));
      gload_lds16(gk, &Ks[buf][wave * 1024 + i * 512]);
      int vrow = wave * 16 + i * 8 + (lane >> 3);
      const char* gv = (const char*)Vt + (size_t)vrow * (SEQ * 2) +
                       (size_t)kv0 * 2 +
                       ((((lane & 7) << 4)) ^ ((vrow & 7) << 4));
      gload_lds16(gv, &Vts[buf][wave * 1024 + i * 512]);
    }
  };

  bf16x8 qf[4];
  stage(0, kvbase);
  {
    const u16* qp = Q + (size_t)(m0 + wave * 16 + lm) * DOUT + 8 * g;
#pragma unroll
    for (int t = 0; t < 4; ++t) qf[t] = glbu8(qp + t * 32);
  }
  asm volatile("s_waitcnt vmcnt(0)" ::: "memory");
  __syncthreads();

  f32x4 o[8];
#pragma unroll
  for (int nb = 0; nb < 8; ++nb) o[nb] = (f32x4){0.f, 0.f, 0.f, 0.f};
  float mr = -1e30f, lr = 0.f;   // scalars: lane owns one q-row

  u16* pw = Ps[wave];
  char* pwb = reinterpret_cast<char*>(pw) + lm * 128;
  const int pswz = (lm & 7) << 4;
  int cur = 0;

  for (int it = 0; it < NIT; ++it) {
    if (it + 1 < NIT) stage(cur ^ 1, kvbase + (it + 1) * KVTILE);

    const u16* ks = Ks[cur];
    const u16* vs = Vts[cur];

    // ---- S^T = K Q^T  (swapped operands; lane owns q-row m0+wave*16+lm)
    f32x4 s[4];
#pragma unroll
    for (int cb = 0; cb < 4; ++cb) {
      f32x4 a = (f32x4){0.f, 0.f, 0.f, 0.f};
      int krow = cb * 16 + lm;
#pragma unroll
      for (int t = 0; t < 4; ++t) {
        bf16x8 b = ldsu8(ks, krow * 256 +
                             (((t * 32 + 8 * g) * 2) ^ ((krow & 7) << 4)));
        a = __builtin_amdgcn_mfma_f32_16x16x32_bf16(b, qf[t], a, 0, 0, 0);
      }
      s[cb] = a;            // log2-units (Q pre-scaled)
    }

    // ---- softmax for this lane's q-row: in-lane tree + 2 shuffles
    float c0 = fmaxf(fmaxf(s[0][0], s[0][1]), fmaxf(s[0][2], s[0][3]));
    float c1 = fmaxf(fmaxf(s[1][0], s[1][1]), fmaxf(s[1][2], s[1][3]));
    float c2 = fmaxf(fmaxf(s[2][0], s[2][1]), fmaxf(s[2][2], s[2][3]));
    float c3 = fmaxf(fmaxf(s[3][0], s[3][1]), fmaxf(s[3][2], s[3][3]));
    float rm = fmaxf(fmaxf(c0, c1), fmaxf(c2, c3));
    rm = fmaxf(rm, __shfl_xor(rm, 16));
    rm = fmaxf(rm, __shfl_xor(rm, 32));

    if (__any(rm - mr > RESCALE_THR)) {   // first tile + rare growth
      float mn = fmaxf(mr, rm);
      float alpha = exp2f(mr - mn);
      mr = mn;
      lr *= alpha;
#pragma unroll
      for (int nb = 0; nb < 8; ++nb) o[nb] *= alpha;
    }

    // ---- P = exp2(S - m); write b64 per cb, sum tree
    float rsum = 0.f;
#pragma unroll
    for (int cb = 0; cb < 4; ++cb) {
      float p0 = exp2f(s[cb][0] - mr);
      float p1 = exp2f(s[cb][1] - mr);
      float p2 = exp2f(s[cb][2] - mr);
      float p3 = exp2f(s[cb][3] - mr);
      u16x4 w = { bfc(p0), bfc(p1), bfc(p2), bfc(p3) };
      *reinterpret_cast<u16x4*>(pwb + ((cb * 32 + g * 8) ^ pswz)) = w;
      rsum += (p0 + p1) + (p2 + p3);
    }
    rsum += __shfl_xor(rsum, 16);
    rsum += __shfl_xor(rsum, 32);
    lr += rsum;

    asm volatile("s_waitcnt lgkmcnt(0)" ::: "memory");
    __builtin_amdgcn_sched_barrier(0);

    // ---- O^T += V^T P
#pragma unroll
    for (int t = 0; t < 2; ++t) {
      bf16x8 pb = ldsu8(pw, lm * 128 + ((t * 64 + g * 16) ^ pswz));
#pragma unroll
      for (int nb = 0; nb < 8; ++nb) {
        int vrow = nb * 16 + lm;
        bf16x8 vb = ldsu8(vs, vrow * 128 +
                              (((t * 32 + 8 * g) * 2) ^ ((vrow & 7) << 4)));
        o[nb] = __builtin_amdgcn_mfma_f32_16x16x32_bf16(vb, pb, o[nb], 0, 0, 0);
      }
    }

    asm volatile("s_waitcnt vmcnt(0)" ::: "memory");
    __syncthreads();
    cur ^= 1;
  }

  // ---- store partials: lane holds O[q=m0+wave*16+lm][d=nb*16+g*4+r]
  const size_t ob = (size_t)split * SEQ * DOUT;
  const int m = m0 + wave * 16 + lm;
#pragma unroll
  for (int nb = 0; nb < 8; ++nb) {
    u16x4 w = { bfc(o[nb][0]), bfc(o[nb][1]), bfc(o[nb][2]), bfc(o[nb][3]) };
    *reinterpret_cast<u16x4*>(Op + ob + (size_t)m * DOUT + nb * 16 + g * 4) = w;
  }
  if (g == 0) {
    Mb[split * SEQ + m] = mr;   // log2-units
    Lb[split * SEQ + m] = lr;
  }
}

// ---------------------------------------------------------------- kernel 3
__global__ __launch_bounds__(256) void k_combine(const u16* __restrict__ Op,
                                                 const float* __restrict__ Mb,
                                                 const float* __restrict__ Lb,
                                                 float* __restrict__ out) {
  int idx = blockIdx.x * 256 + threadIdx.x;   // over SEQ*DOUT
  int srow = idx >> 7;
  float M = -1e30f;
#pragma unroll
  for (int s = 0; s < NSPLIT; ++s) M = fmaxf(M, Mb[s * SEQ + srow]);
  float num = 0.f, den = 0.f;
  const size_t st = (size_t)SEQ * DOUT;
#pragma unroll
  for (int s = 0; s < NSPLIT; ++s) {
    float e = exp2f(Mb[s * SEQ + srow] - M);
    den += Lb[s * SEQ + srow] * e;
    num += bf2f(Op[s * st + idx]) * e;
  }
  out[idx] = num / den;
}

// ---------------------------------------------------------------- launch
extern "C" void kernel_launch(void* const* d_in, const int* in_sizes, int n_in,
                              void* d_out, int out_size, void* d_ws, size_t ws_size,
                              hipStream_t stream) {
  const float* x  = (const float*)d_in[0];
  const float* wq = (const float*)d_in[1];
  const float* wk = (const float*)d_in[2];
  const float* wv = (const float*)d_in[3];
  char* ws = (char*)d_ws;

  // workspace layout (bytes), total exactly 23.25 MiB (proven footprint):
  //  [0,      768K)        Wt bf16 [3][128][1024]
  //  [768K,   +2M)         Q  bf16 [8192][128]   (pre-scaled by QK_SCALE)
  //  [768K+2M,+2M)         K  bf16 [8192][128]
  //  [768K+4M,+2M)         Vt bf16 [128][8192]       (ends 6.75M)
  //  [6.75M,  +256K)       Mb f32 [8][8192]
  //  [6.75M+256K, +256K)   Lb f32 [8][8192]          (ends 7.25M)
  //  [7.25M,  +16M)        Xb bf16 [8192][1024]  ALIASED with
  //                        Op bf16 [8][8192][128] (Xb dead before k_attn)
  const size_t MB = (size_t)1 << 20;
  u16*   Wt = (u16*)(ws);
  u16*   Q  = (u16*)(ws + 768 * 1024);
  u16*   K  = (u16*)(ws + 768 * 1024 + 2 * MB);
  u16*   Vt = (u16*)(ws + 768 * 1024 + 4 * MB);
  float* Mb = (float*)(ws + 768 * 1024 + 6 * MB);
  float* Lb = (float*)(ws + 768 * 1024 + 6 * MB + 256 * 1024);
  u16*   Xb = (u16*)(ws + 7 * MB + 256 * 1024);
  u16*   Op = (u16*)(ws + 7 * MB + 256 * 1024);
  float* out = (float*)d_out;

  k_wtrans<<<dim3((DIN * DOUT) / 256, 3), 256, 0, stream>>>(wq, wk, wv, Wt);
  k_xcast<<<dim3((SEQ * DIN) / (256 * 8)), 256, 0, stream>>>(x, Xb);
  k_gemm<<<dim3(SEQ / 64, 4), 256, 0, stream>>>(Xb, Wt, Q, K, Vt);
  k_attn<<<dim3(SEQ / QTILE, NSPLIT), 512, 0, stream>>>(Q, K, Vt, Op, Mb, Lb);
  k_combine<<<dim3((SEQ * DOUT) / 256), 256, 0, stream>>>(Op, Mb, Lb, out);
}